// Round 4
// baseline (949.357 us; speedup 1.0000x reference)
//
#include <hip/hip_runtime.h>
#include <hip/hip_bf16.h>

typedef __attribute__((ext_vector_type(8))) short bf16x8;
typedef __attribute__((ext_vector_type(4))) float f32x4;

#define DEVI __device__ __forceinline__

DEVI short f2bf(float f) {
  union { float f; unsigned u; } v; v.f = f;
  unsigned r = v.u + 0x7FFFu + ((v.u >> 16) & 1u);
  return (short)(r >> 16);
}

DEVI void gl16(const void* g, void* l) {
  __builtin_amdgcn_global_load_lds((const __attribute__((address_space(1))) unsigned*)g,
                                   (__attribute__((address_space(3))) unsigned*)l,
                                   16, 0, 0);
}

DEVI float exp2a(float x) { float r; asm("v_exp_f32 %0, %1" : "=v"(r) : "v"(x)); return r; }

DEVI unsigned pk2(float lo, float hi) {
  union { __hip_bfloat162 h; unsigned u; } v;
  float2 f; f.x = lo; f.y = hi;
  v.h = __float22bfloat162_rn(f);
  return v.u;
}

union U8 { unsigned u[4]; bf16x8 v; };
DEVI bf16x8 mk8(unsigned a, unsigned b, unsigned c, unsigned d) {
  U8 x; x.u[0]=a; x.u[1]=b; x.u[2]=c; x.u[3]=d; return x.v;
}

// ---------------- conversion kernels ----------------

__global__ __launch_bounds__(256) void conv_x_k(const float* __restrict__ x,
                                                short* __restrict__ xb) {
  long i = (long)blockIdx.x * 256 + threadIdx.x;
  const float4* xf = (const float4*)x;
  float4 a = xf[i * 2], c = xf[i * 2 + 1];
  bf16x8 r;
  r[0] = f2bf(a.x); r[1] = f2bf(a.y); r[2] = f2bf(a.z); r[3] = f2bf(a.w);
  r[4] = f2bf(c.x); r[5] = f2bf(c.y); r[6] = f2bf(c.z); r[7] = f2bf(c.w);
  *(bf16x8*)(xb + i * 8) = r;
}

__global__ __launch_bounds__(256) void conv_wT_k(const float* __restrict__ w,
                                                 short* __restrict__ wT, int Ncols) {
  int i = blockIdx.x * 256 + threadIdx.x;
  if (i >= Ncols * 512) return;
  int n = i >> 9, k = i & 511;
  wT[i] = f2bf(w[k * Ncols + n]);
}

// biasT[h][m][n] = btab[relidx(n_query, m_key)*16+h] * log2(e); -1e30 for m>=49
__global__ __launch_bounds__(256) void fill_biasT(const float* __restrict__ btab,
                                                  float* __restrict__ biasT) {
  int i = blockIdx.x * 256 + threadIdx.x;   // 16*64*64
  int h = i >> 12, m = (i >> 6) & 63, n = i & 63;
  float v;
  if (m >= 49) {
    v = -1e30f;
  } else {
    int nn = n > 48 ? 48 : n;
    int ni = nn / 7, nj = nn - ni * 7;
    int mi = m / 7,  mj = m - mi * 7;
    int idx = (ni - mi + 6) * 13 + (nj - mj + 6);
    v = btab[idx * 16 + h] * 1.4426950408889634f;
  }
  biasT[i] = v;
}

// ---------------- 128x128 bf16 GEMM (m97 structure + LDS XOR swizzle), B^T input ----
// LDS tile [128][32] bf16 (64B rows). Swizzle: LDS slot (row, c) holds global 16B
// chunk (row, c ^ ((row>>1)&3)); reads XOR g with (l15>>1)&3. Each fragment read then
// tiles a contiguous 1KB region (<=2-way bank aliasing = free) instead of 8-way conflicts.

template <int EPI>
__global__ __launch_bounds__(256, 2)
void gemm128(const short* __restrict__ A, const short* __restrict__ Bt,
             const float* __restrict__ bias, void* __restrict__ outp, int ctiles) {
  __shared__ short As[4096];
  __shared__ short Bs[4096];

  const int nwg = gridDim.x;
  const int w = blockIdx.x;
  const int chunk = nwg >> 3;
  const int tid = (w & 7) * chunk + (w >> 3);
  const int rt = tid / ctiles, ct = tid % ctiles;
  const long m0 = (long)rt * 128;
  const int n0 = ct * 128;

  const int t = threadIdx.x;
  const int lane = t & 63;
  const int wv = t >> 6;
  const int wm = wv >> 1, wn = wv & 1;
  const int l15 = lane & 15, g = lane >> 4;

  // staging: thread t -> LDS row rA0 = t>>2, 16B slot t&3 (linear dest).
  // source chunk pre-swizzled: cSw = (t&3) ^ ((row>>1)&3); row+64 leaves it unchanged.
  const int rA0 = t >> 2;
  const int cSw = (t & 3) ^ ((t >> 3) & 3);
  const short* Ag0 = A + (m0 + rA0) * 512 + cSw * 8;
  const short* Ag1 = A + (m0 + rA0 + 64) * 512 + cSw * 8;
  const short* Bg0 = Bt + (long)(n0 + rA0) * 512 + cSw * 8;
  const short* Bg1 = Bt + (long)(n0 + rA0 + 64) * 512 + cSw * 8;
  short* Al0 = As + t * 8;
  short* Al1 = As + (t + 256) * 8;
  short* Bl0 = Bs + t * 8;
  short* Bl1 = Bs + (t + 256) * 8;

  // fragment reads: XOR the 16B-slot index with (row>>1)&3 = (l15>>1)&3 (i-invariant)
  const int xl = (l15 >> 1) & 3;
  const short* aRd = As + (wm * 64 + l15) * 32 + (g ^ xl) * 8;
  const short* bRd = Bs + (wn * 64 + l15) * 32 + (g ^ xl) * 8;

  f32x4 acc[4][4] = {};

  for (int kk = 0; kk < 512; kk += 32) {
    __syncthreads();
    gl16(Ag0 + kk, Al0);
    gl16(Ag1 + kk, Al1);
    gl16(Bg0 + kk, Bl0);
    gl16(Bg1 + kk, Bl1);
    __syncthreads();
    bf16x8 a[4], b[4];
#pragma unroll
    for (int i = 0; i < 4; ++i) a[i] = *(const bf16x8*)(aRd + i * 512);
#pragma unroll
    for (int j = 0; j < 4; ++j) b[j] = *(const bf16x8*)(bRd + j * 512);
#pragma unroll
    for (int i = 0; i < 4; ++i)
#pragma unroll
      for (int j = 0; j < 4; ++j)
        acc[i][j] = __builtin_amdgcn_mfma_f32_16x16x32_bf16(a[i], b[j], acc[i][j], 0, 0, 0);
  }

  if (EPI == 0) {
    short* qkv = (short*)outp;
#pragma unroll
    for (int i = 0; i < 4; ++i)
#pragma unroll
      for (int r = 0; r < 4; ++r) {
        int row = (int)m0 + wm * 64 + i * 16 + g * 4 + r;
        int b = row / 49, n = row - b * 49;
#pragma unroll
        for (int j = 0; j < 4; ++j) {
          int col = n0 + wn * 64 + j * 16 + l15;
          float val = acc[i][j][r] + bias[col];
          int ii = col >> 9, h = (col >> 5) & 15, d = col & 31;
          qkv[(long)((b * 16 + h) * 3 + ii) * 1568 + n * 32 + d] = f2bf(val);
        }
      }
  } else {
    float* out = (float*)outp;
#pragma unroll
    for (int i = 0; i < 4; ++i)
#pragma unroll
      for (int r = 0; r < 4; ++r) {
        long row = m0 + wm * 64 + i * 16 + g * 4 + r;
#pragma unroll
        for (int j = 0; j < 4; ++j) {
          int col = n0 + wn * 64 + j * 16 + l15;
          out[row * 512 + col] = acc[i][j][r] + bias[col];
        }
      }
  }
}

// ---------------- attention: swapped-QK^T, in-register softmax, no LDS, no barriers ----

__global__ __launch_bounds__(256, 3)
void attn49(const short* __restrict__ qkvb, const float* __restrict__ biasT,
            short* __restrict__ ao) {
  const int t = threadIdx.x, lane = t & 63, wv = t >> 6;
  const int l15 = lane & 15, g = lane >> 4, g4 = g * 4;
  const int b = blockIdx.x >> 2;
  const int h = (blockIdx.x & 3) * 4 + wv;

  const short* qb = qkvb + (long)(b * 16 + h) * 3 * 1568;
  const short* kb = qb + 1568;
  const short* vb = kb + 1568;

  // Q/K fragments (rows clamped to 48; junk killed by bias)
  bf16x8 qf[4], kf[4];
#pragma unroll
  for (int i = 0; i < 4; ++i) {
    int row = i * 16 + l15; row = row > 48 ? 48 : row;
    kf[i] = *(const bf16x8*)(kb + row * 32 + g * 8);
    qf[i] = *(const bf16x8*)(qb + row * 32 + g * 8);
  }

  // V B-fragments: vf[kt][dt][e] = V[sigma(kt,g,e)][dt*16+l15], clamped
  bf16x8 vf[2][2];
#pragma unroll
  for (int kt = 0; kt < 2; ++kt)
#pragma unroll
    for (int hi = 0; hi < 2; ++hi)
#pragma unroll
      for (int r = 0; r < 4; ++r) {
        int m = kt * 32 + hi * 16 + g4 + r;
        m = m > 48 ? 48 : m;
#pragma unroll
        for (int dt = 0; dt < 2; ++dt)
          vf[kt][dt][hi * 4 + r] = vb[m * 32 + dt * 16 + l15];
      }

  // S = K·Q^T (swapped): rows m = key, cols n = query
  f32x4 s[4][4] = {};
#pragma unroll
  for (int i = 0; i < 4; ++i)
#pragma unroll
    for (int j = 0; j < 4; ++j)
      s[i][j] = __builtin_amdgcn_mfma_f32_16x16x32_bf16(kf[i], qf[j], s[i][j], 0, 0, 0);

  // p = exp2(s*scale*log2e + biasT); column sums (over m) in-lane + 2 shfl
  const float* biasH = biasT + h * 4096;
  float sum[4] = {0.f, 0.f, 0.f, 0.f};
#pragma unroll
  for (int i = 0; i < 4; ++i)
#pragma unroll
    for (int r = 0; r < 4; ++r) {
      int m = i * 16 + g4 + r;
      const float* bp = biasH + m * 64 + l15;
#pragma unroll
      for (int j = 0; j < 4; ++j) {
        float p = exp2a(fmaf(s[i][j][r], 0.06375871f, bp[j * 16]));
        s[i][j][r] = p;
        sum[j] += p;
      }
    }
#pragma unroll
  for (int j = 0; j < 4; ++j) {
    sum[j] += __shfl_xor(sum[j], 16);
    sum[j] += __shfl_xor(sum[j], 32);
    sum[j] = 1.f / sum[j];
  }

  // normalize + pack to bf16 pairs (pure in-lane)
  unsigned pk[4][4][2];
#pragma unroll
  for (int j = 0; j < 4; ++j)
#pragma unroll
    for (int i = 0; i < 4; ++i) {
      pk[j][i][0] = pk2(s[i][j][0] * sum[j], s[i][j][1] * sum[j]);
      pk[j][i][1] = pk2(s[i][j][2] * sum[j], s[i][j][3] * sum[j]);
    }

  // O = P·V
  f32x4 o[4][2] = {};
#pragma unroll
  for (int j = 0; j < 4; ++j) {
    bf16x8 a0 = mk8(pk[j][0][0], pk[j][0][1], pk[j][1][0], pk[j][1][1]);
    bf16x8 a1 = mk8(pk[j][2][0], pk[j][2][1], pk[j][3][0], pk[j][3][1]);
    o[j][0] = __builtin_amdgcn_mfma_f32_16x16x32_bf16(a0, vf[0][0], o[j][0], 0, 0, 0);
    o[j][0] = __builtin_amdgcn_mfma_f32_16x16x32_bf16(a1, vf[1][0], o[j][0], 0, 0, 0);
    o[j][1] = __builtin_amdgcn_mfma_f32_16x16x32_bf16(a0, vf[0][1], o[j][1], 0, 0, 0);
    o[j][1] = __builtin_amdgcn_mfma_f32_16x16x32_bf16(a1, vf[1][1], o[j][1], 0, 0, 0);
  }

  // write attn_out [M,512] bf16: col = h*32 + d
#pragma unroll
  for (int j = 0; j < 4; ++j)
#pragma unroll
    for (int r = 0; r < 4; ++r) {
      int n = j * 16 + g4 + r;
      if (n < 49) {
        long off = ((long)b * 49 + n) * 512 + h * 32 + l15;
        ao[off]      = f2bf(o[j][0][r]);
        ao[off + 16] = f2bf(o[j][1][r]);
      }
    }
}

// ---------------- host ----------------

extern "C" void kernel_launch(void* const* d_in, const int* in_sizes, int n_in,
                              void* d_out, int out_size, void* d_ws, size_t ws_size,
                              hipStream_t stream) {
  (void)in_sizes; (void)n_in; (void)out_size; (void)ws_size;
  const float* x      = (const float*)d_in[0];
  const float* w_qkv  = (const float*)d_in[1];
  const float* b_qkv  = (const float*)d_in[2];
  const float* w_proj = (const float*)d_in[3];
  const float* b_proj = (const float*)d_in[4];
  const float* btab   = (const float*)d_in[5];

  char* ws = (char*)d_ws;
  short* xb  = (short*)ws;                                        // 205,520,896 B
  short* wqT = (short*)(ws + 205520896L);                         //   1,572,864 B
  short* wpT = (short*)(ws + 205520896L + 1572864L);              //     524,288 B
  short* qkv = (short*)(ws + 205520896L + 1572864L + 524288L);    // 616,562,688 B
  short* ao  = xb;                     // alias: x_bf16 dead after QKV GEMM
  float* biasT = (float*)wqT;          // alias: wqT dead after QKV GEMM (256 KB)

  conv_x_k <<<50176, 256, 0, stream>>>(x, xb);
  conv_wT_k<<<3072, 256, 0, stream>>>(w_qkv, wqT, 1536);
  conv_wT_k<<<1024, 256, 0, stream>>>(w_proj, wpT, 512);
  gemm128<0><<<18816, 256, 0, stream>>>(xb, wqT, b_qkv, (void*)qkv, 12);
  fill_biasT<<<256, 256, 0, stream>>>(btab, biasT);
  attn49   <<<16384, 256, 0, stream>>>(qkv, biasT, ao);
  gemm128<1><<<6272, 256, 0, stream>>>(ao, wpT, b_proj, d_out, 4);
}